// Round 1
// baseline (531.780 us; speedup 1.0000x reference)
//
#include <hip/hip_runtime.h>

// DiffeomorphicTransform: flow = velocity/2^7; 7x { grid = sample_grid + flow*rf;
// flow = flow + trilerp(flow, grid) }  (border clamp, align_corners=True)
//
// Layouts: flow/velocity [C=3][D=128][H=160][W=128] (channel stride N),
// sample_grid [D][H][W][3] (x,y,z innermost). One thread per voxel.

constexpr int D = 128, H = 160, W = 128;
constexpr int N = D * H * W;          // 2,621,440 voxels
constexpr int C = 3;

__global__ __launch_bounds__(256)
void diffeo_step(const float* __restrict__ src,   // [3][N] flow (unscaled by `scale`)
                 const float* __restrict__ grid,  // [N][3]
                 const float* __restrict__ rf_p,  // scalar range_flow
                 float* __restrict__ dst,         // [3][N]
                 float scale)                     // 1/128 on step 1, else 1.0
{
    int i = blockIdx.x * blockDim.x + threadIdx.x;
    if (i >= N) return;
    const float rf = rf_p[0];

    // current flow at this voxel (apply deferred scale)
    const float fx = src[i]         * scale;
    const float fy = src[i + N]     * scale;
    const float fz = src[i + 2 * N] * scale;

    // sampling position, normalized -> voxel coords, border clamp (align_corners=True)
    const float gx = grid[3 * i + 0] + fx * rf;
    const float gy = grid[3 * i + 1] + fy * rf;
    const float gz = grid[3 * i + 2] + fz * rf;

    const float ix = fminf(fmaxf((gx + 1.0f) * 0.5f * (float)(W - 1), 0.0f), (float)(W - 1));
    const float iy = fminf(fmaxf((gy + 1.0f) * 0.5f * (float)(H - 1), 0.0f), (float)(H - 1));
    const float iz = fminf(fmaxf((gz + 1.0f) * 0.5f * (float)(D - 1), 0.0f), (float)(D - 1));

    const float x0f = floorf(ix), y0f = floorf(iy), z0f = floorf(iz);
    const float wx = ix - x0f, wy = iy - y0f, wz = iz - z0f;
    const int x0 = (int)x0f, y0 = (int)y0f, z0 = (int)z0f;
    const int x1 = min(x0 + 1, W - 1);
    const int y1 = min(y0 + 1, H - 1);
    const int z1 = min(z0 + 1, D - 1);

    const int b00 = (z0 * H + y0) * W;   // z0,y0 row base
    const int b01 = (z0 * H + y1) * W;
    const int b10 = (z1 * H + y0) * W;
    const int b11 = (z1 * H + y1) * W;

    const float omx = 1.0f - wx, omy = 1.0f - wy, omz = 1.0f - wz;
    const float w000 = omz * omy * omx, w001 = omz * omy * wx;
    const float w010 = omz * wy  * omx, w011 = omz * wy  * wx;
    const float w100 = wz  * omy * omx, w101 = wz  * omy * wx;
    const float w110 = wz  * wy  * omx, w111 = wz  * wy  * wx;

    const float base[3] = {fx, fy, fz};
#pragma unroll
    for (int c = 0; c < C; ++c) {
        const float* __restrict__ s = src + c * N;
        float v = w000 * s[b00 + x0] + w001 * s[b00 + x1]
                + w010 * s[b01 + x0] + w011 * s[b01 + x1]
                + w100 * s[b10 + x0] + w101 * s[b10 + x1]
                + w110 * s[b11 + x0] + w111 * s[b11 + x1];
        // gathered values carry the deferred scale too (trilerp is linear)
        dst[c * N + i] = base[c] + v * scale;
    }
}

extern "C" void kernel_launch(void* const* d_in, const int* in_sizes, int n_in,
                              void* d_out, int out_size, void* d_ws, size_t ws_size,
                              hipStream_t stream)
{
    const float* vel  = (const float*)d_in[0];   // [1,3,128,160,128]
    const float* grid = (const float*)d_in[1];   // [1,128,160,128,3]
    const float* rf   = (const float*)d_in[2];   // scalar
    float* out = (float*)d_out;                  // [1,3,128,160,128]
    float* ws  = (float*)d_ws;                   // needs 3*N*4 = 31.5 MB

    const dim3 blk(256);
    const dim3 grd((N + 255) / 256);

    // step 1: velocity (deferred /128) -> out
    diffeo_step<<<grd, blk, 0, stream>>>(vel, grid, rf, out, 1.0f / 128.0f);
    // steps 2..7 ping-pong: out->ws, ws->out, ... ; step 7 ends in d_out
    float* bufs[2] = {out, ws};
    for (int it = 2; it <= 7; ++it) {
        float* s = bufs[it & 1];        // it=2: out, it=3: ws, ...
        float* d = bufs[(it + 1) & 1];  // it=2: ws,  it=3: out, ...
        diffeo_step<<<grd, blk, 0, stream>>>(s, grid, rf, d, 1.0f);
    }
}